// Round 2
// baseline (118.292 us; speedup 1.0000x reference)
//
#include <hip/hip_runtime.h>

#define T_ 16
#define B_ 32
#define N_ 4096
#define NT 20
#define F_ 25
#define H_ 8
#define HID_ 128
#define PSTR 9               // padded pool row stride (spreads banks for distinct-ty reads)
#define PPT 4                // points per thread
#define BT 1024              // block threads (16 waves -> needs VGPR <= 128)

// Tiny fully-unrolled MLP layer: out = relu(in @ W + b), W is (NI x 8) row-major.
// W/b are wave-uniform with compile-time indices -> scalar loads (s_load), no VGPR cost.
template<int NI>
__device__ __forceinline__ void layer(const float* in,
                                      const float* __restrict__ W,
                                      const float* __restrict__ b,
                                      float* out) {
#pragma unroll
  for (int j = 0; j < H_; j++) {
    float a = b[j];
#pragma unroll
    for (int f = 0; f < NI; f++) a = fmaf(in[f], W[f*H_ + j], a);
    out[j] = fmaxf(a, 0.0f);
  }
}

// One block per (t,b) slot: MLP1 -> LDS pool1 -> MLP2 (h3 kept in regs) -> LDS pool2
// -> fused 160x128 GEMV epilogue. No workspace, no global atomics.
extern "C" __global__ __launch_bounds__(BT)
void kFused(const float* __restrict__ pts,
            const float* __restrict__ W1, const float* __restrict__ b1,
            const float* __restrict__ W2, const float* __restrict__ b2,
            const float* __restrict__ W3, const float* __restrict__ b3,
            const float* __restrict__ W4, const float* __restrict__ b4,
            const float* __restrict__ W5, const float* __restrict__ b5,
            const float* __restrict__ W6, const float* __restrict__ b6,
            const float* __restrict__ Wout, const float* __restrict__ bout,
            float* __restrict__ out)
{
  __shared__ int pool1[NT*PSTR];   // nonneg float bits: int max == float max; 0 == 0.0f
  __shared__ int pool2[NT*PSTR];
  const int tid = threadIdx.x;
  const int tb = blockIdx.x;
  for (int i = tid; i < NT*PSTR; i += BT) { pool1[i] = 0; pool2[i] = 0; }
  __syncthreads();

  const float* base = pts + (size_t)tb * (N_ * F_);
  float h3r[PPT][H_];   // statically indexed (full unroll) -> registers
  int   tyr[PPT];

  // ---- Phase 1: per-point MLP1 + pool1 ----
#pragma unroll
  for (int r = 0; r < PPT; r++) {
    const int p = tid + r*BT;
    const float* px = base + p*F_;
    float xv[F_];
#pragma unroll
    for (int f = 0; f < F_; f++) xv[f] = px[f];

    int ty = 0; float best = xv[4];
#pragma unroll
    for (int k = 1; k < NT; k++) if (xv[4+k] > best) { best = xv[4+k]; ty = k; }
    const bool valid = (xv[F_-1] != 0.0f);

    float t1[H_], t2[H_];
    layer<F_>(xv, W1, b1, t1);
    layer<H_>(t1, W2, b2, t2);
    layer<H_>(t2, W3, b3, t1);

    tyr[r] = valid ? ty : -1;
#pragma unroll
    for (int j = 0; j < H_; j++) h3r[r][j] = valid ? t1[j] : 0.0f;
    if (valid) {
#pragma unroll
      for (int j = 0; j < H_; j++)
        atomicMax(&pool1[ty*PSTR + j], __float_as_int(t1[j]));
    }
  }
  __syncthreads();

  // ---- Phase 2: concat(h3, pooled1[ty]) -> MLP2 + pool2 ----
#pragma unroll
  for (int r = 0; r < PPT; r++) {
    const int ty = tyr[r];
    if (ty >= 0) {               // invalid points contribute 0 -> no-op for max pool
      float x16[2*H_];
#pragma unroll
      for (int j = 0; j < H_; j++) x16[j] = h3r[r][j];
#pragma unroll
      for (int j = 0; j < H_; j++) x16[H_+j] = __int_as_float(pool1[ty*PSTR + j]);
      float t1[H_], t2[H_];
      layer<2*H_>(x16, W4, b4, t1);
      layer<H_>(t1, W5, b5, t2);
      layer<H_>(t2, W6, b6, t1);
#pragma unroll
      for (int j = 0; j < H_; j++)
        atomicMax(&pool2[ty*PSTR + j], __float_as_int(t1[j]));
    }
  }
  __syncthreads();

  // ---- Stage C: out[tb,:] = relu(pooled2 @ Wout + bout) ----
  if (tid < HID_) {
    float a = bout[tid];
#pragma unroll 4
    for (int k = 0; k < NT*H_; k++) {
      const float v = __int_as_float(pool2[(k >> 3)*PSTR + (k & 7)]);
      a = fmaf(v, Wout[k*HID_ + tid], a);
    }
    out[tb*HID_ + tid] = fmaxf(a, 0.0f);
  }
}

extern "C" void kernel_launch(void* const* d_in, const int* in_sizes, int n_in,
                              void* d_out, int out_size, void* d_ws, size_t ws_size,
                              hipStream_t stream) {
  const float* pts  = (const float*)d_in[0];
  const float* W1   = (const float*)d_in[1];  const float* b1 = (const float*)d_in[2];
  const float* W2   = (const float*)d_in[3];  const float* b2 = (const float*)d_in[4];
  const float* W3   = (const float*)d_in[5];  const float* b3 = (const float*)d_in[6];
  const float* W4   = (const float*)d_in[7];  const float* b4 = (const float*)d_in[8];
  const float* W5   = (const float*)d_in[9];  const float* b5 = (const float*)d_in[10];
  const float* W6   = (const float*)d_in[11]; const float* b6 = (const float*)d_in[12];
  const float* Wout = (const float*)d_in[13]; const float* bout = (const float*)d_in[14];
  float* out = (float*)d_out;

  kFused<<<T_*B_, BT, 0, stream>>>(pts, W1, b1, W2, b2, W3, b3,
                                   W4, b4, W5, b5, W6, b6, Wout, bout, out);
}

// Round 4
// 77.991 us; speedup vs baseline: 1.5167x; 1.5167x over previous
//
#include <hip/hip_runtime.h>

#define T_ 16
#define B_ 32
#define N_ 4096
#define NT 20
#define F_ 25
#define H_ 8
#define HID_ 128
#define PSTR 9               // padded LDS pool stride (spreads banks across ty rows)
#define TBN_ (T_*B_*N_)      // 2097152 points
#define NSEG_ (T_*B_*NT)     // 10240 segments
#define SEGF_ (NT*H_)        // 160 floats per (t,b) pooled row

// bf16 pack/unpack (values are nonneg, finite: relu outputs)
__device__ __forceinline__ unsigned short f2bf(float x) {
  unsigned u = __float_as_uint(x);
  u += 0x7fffu + ((u >> 16) & 1u);     // round-to-nearest-even
  return (unsigned short)(u >> 16);
}
__device__ __forceinline__ float bf2f(unsigned s) {
  return __uint_as_float(s << 16);
}

// Tiny fully-unrolled MLP layer: out = relu(in @ W + b), W is (NI x 8) row-major.
// W/b wave-uniform + compile-time indices -> scalar loads.
template<int NI>
__device__ __forceinline__ void layer(const float* in, const float* __restrict__ W,
                                      const float* __restrict__ b, float* out) {
#pragma unroll
  for (int j = 0; j < H_; j++) {
    float a = b[j];
#pragma unroll
    for (int f = 0; f < NI; f++) a = fmaf(in[f], W[f*H_ + j], a);
    out[j] = fmaxf(a, 0.0f);
  }
}

// Shared: coalesced float4 staging of 256 points (6400 floats) into xs.
__device__ __forceinline__ void stagePoints(const float* __restrict__ gblk,
                                            float* xs, int tid) {
  const float4* g4 = (const float4*)gblk;
  float4* x4 = (float4*)xs;
#pragma unroll
  for (int k = 0; k < 6; k++) x4[tid + k*256] = g4[tid + k*256];
  xs[6144 + tid] = gblk[6144 + tid];
}

// Stage A: MLP1 (25->8->8->8) + pool1; stores h3 (bf16x8 = uint4) + ty/valid byte.
extern "C" __global__ __launch_bounds__(256)
void kA(const float* __restrict__ pts,
        const float* __restrict__ W1, const float* __restrict__ b1,
        const float* __restrict__ W2, const float* __restrict__ b2,
        const float* __restrict__ W3, const float* __restrict__ b3,
        int* __restrict__ pool1, uint4* __restrict__ hbuf,
        unsigned char* __restrict__ tbuf, int storeH)
{
  __shared__ float xs[256 * F_];
  __shared__ int lp[NT*PSTR];          // nonneg float bits: int max == float max
  const int tid = threadIdx.x;
  for (int i = tid; i < NT*PSTR; i += 256) lp[i] = 0;

  stagePoints(pts + (size_t)blockIdx.x * (256*F_), xs, tid);
  __syncthreads();

  float xv[F_];
#pragma unroll
  for (int f = 0; f < F_; f++) xv[f] = xs[tid*F_ + f];   // stride-25: free 2-way alias

  int ty = 0; float best = xv[4];
#pragma unroll
  for (int k = 1; k < NT; k++) if (xv[4+k] > best) { best = xv[4+k]; ty = k; }
  const bool valid = (xv[F_-1] != 0.0f);

  float t1[H_], t2[H_];
  layer<F_>(xv, W1, b1, t1);
  layer<H_>(t1, W2, b2, t2);
  layer<H_>(t2, W3, b3, t1);           // t1 = h3
  if (!valid) {
#pragma unroll
    for (int j = 0; j < H_; j++) t1[j] = 0.0f;
  }

  const int p = blockIdx.x*256 + tid;
  if (storeH) {
    uint4 v;
    v.x = (unsigned)f2bf(t1[0]) | ((unsigned)f2bf(t1[1]) << 16);
    v.y = (unsigned)f2bf(t1[2]) | ((unsigned)f2bf(t1[3]) << 16);
    v.z = (unsigned)f2bf(t1[4]) | ((unsigned)f2bf(t1[5]) << 16);
    v.w = (unsigned)f2bf(t1[6]) | ((unsigned)f2bf(t1[7]) << 16);
    hbuf[p] = v;
    tbuf[p] = (unsigned char)(ty | (valid ? 0x80 : 0));
  }
  if (valid) {
#pragma unroll
    for (int j = 0; j < H_; j++) atomicMax(&lp[ty*PSTR + j], __float_as_int(t1[j]));
  }
  __syncthreads();

  const int tb = blockIdx.x >> 4;
  int* gp = pool1 + tb*SEGF_;
  for (int i = tid; i < SEGF_; i += 256) {
    int v = lp[(i >> 3)*PSTR + (i & 7)];
    if (v > 0) atomicMax(&gp[i], v);
  }
}

// Stage B: concat(h3, pooled1[ty]) -> MLP2 (16->8->8->8) + pool2.
extern "C" __global__ __launch_bounds__(256)
void kB(const uint4* __restrict__ hbuf, const unsigned char* __restrict__ tbuf,
        const int* __restrict__ pool1,
        const float* __restrict__ W4, const float* __restrict__ b4,
        const float* __restrict__ W5, const float* __restrict__ b5,
        const float* __restrict__ W6, const float* __restrict__ b6,
        int* __restrict__ pool2)
{
  __shared__ float pl[NT*PSTR];
  __shared__ int lp[NT*PSTR];
  const int tid = threadIdx.x;
  const int tb = blockIdx.x >> 4;
  for (int i = tid; i < NT*PSTR; i += 256) lp[i] = 0;
  for (int i = tid; i < SEGF_; i += 256)
    pl[(i >> 3)*PSTR + (i & 7)] = __int_as_float(pool1[tb*SEGF_ + i]);
  __syncthreads();

  const int p = blockIdx.x*256 + tid;
  const unsigned char tv = tbuf[p];
  if (tv & 0x80) {                     // invalid -> zero contribution -> skip
    const int ty = tv & 0x7f;
    const uint4 v = hbuf[p];
    float x16[2*H_];
    x16[0] = bf2f(v.x & 0xffffu); x16[1] = bf2f(v.x >> 16);
    x16[2] = bf2f(v.y & 0xffffu); x16[3] = bf2f(v.y >> 16);
    x16[4] = bf2f(v.z & 0xffffu); x16[5] = bf2f(v.z >> 16);
    x16[6] = bf2f(v.w & 0xffffu); x16[7] = bf2f(v.w >> 16);
#pragma unroll
    for (int j = 0; j < H_; j++) x16[H_+j] = pl[ty*PSTR + j];
    float t1[H_], t2[H_];
    layer<2*H_>(x16, W4, b4, t1);
    layer<H_>(t1, W5, b5, t2);
    layer<H_>(t2, W6, b6, t1);
#pragma unroll
    for (int j = 0; j < H_; j++) atomicMax(&lp[ty*PSTR + j], __float_as_int(t1[j]));
  }
  __syncthreads();

  int* gp = pool2 + tb*SEGF_;
  for (int i = tid; i < SEGF_; i += 256) {
    int v = lp[(i >> 3)*PSTR + (i & 7)];
    if (v > 0) atomicMax(&gp[i], v);
  }
}

// Stage B fallback (ws too small): recompute MLP1 from points.
extern "C" __global__ __launch_bounds__(256)
void kBrec(const float* __restrict__ pts,
           const float* __restrict__ W1, const float* __restrict__ b1,
           const float* __restrict__ W2, const float* __restrict__ b2,
           const float* __restrict__ W3, const float* __restrict__ b3,
           const int* __restrict__ pool1,
           const float* __restrict__ W4, const float* __restrict__ b4,
           const float* __restrict__ W5, const float* __restrict__ b5,
           const float* __restrict__ W6, const float* __restrict__ b6,
           int* __restrict__ pool2)
{
  __shared__ float xs[256 * F_];
  __shared__ float pl[NT*PSTR];
  __shared__ int lp[NT*PSTR];
  const int tid = threadIdx.x;
  const int tb = blockIdx.x >> 4;
  for (int i = tid; i < NT*PSTR; i += 256) lp[i] = 0;
  for (int i = tid; i < SEGF_; i += 256)
    pl[(i >> 3)*PSTR + (i & 7)] = __int_as_float(pool1[tb*SEGF_ + i]);

  stagePoints(pts + (size_t)blockIdx.x * (256*F_), xs, tid);
  __syncthreads();

  float xv[F_];
#pragma unroll
  for (int f = 0; f < F_; f++) xv[f] = xs[tid*F_ + f];
  int ty = 0; float best = xv[4];
#pragma unroll
  for (int k = 1; k < NT; k++) if (xv[4+k] > best) { best = xv[4+k]; ty = k; }
  const bool valid = (xv[F_-1] != 0.0f);

  if (valid) {
    float t1[H_], t2[H_];
    layer<F_>(xv, W1, b1, t1);
    layer<H_>(t1, W2, b2, t2);
    layer<H_>(t2, W3, b3, t1);
    float x16[2*H_];
#pragma unroll
    for (int j = 0; j < H_; j++) x16[j] = t1[j];
#pragma unroll
    for (int j = 0; j < H_; j++) x16[H_+j] = pl[ty*PSTR + j];
    layer<2*H_>(x16, W4, b4, t1);
    layer<H_>(t1, W5, b5, t2);
    layer<H_>(t2, W6, b6, t1);
#pragma unroll
    for (int j = 0; j < H_; j++) atomicMax(&lp[ty*PSTR + j], __float_as_int(t1[j]));
  }
  __syncthreads();

  int* gp = pool2 + tb*SEGF_;
  for (int i = tid; i < SEGF_; i += 256) {
    int v = lp[(i >> 3)*PSTR + (i & 7)];
    if (v > 0) atomicMax(&gp[i], v);
  }
}

// Stage C: out(512,128) = relu(pooled2(512,160) @ Wout(160,128) + bout)
extern "C" __global__ __launch_bounds__(128)
void kC(const int* __restrict__ pool2, const float* __restrict__ Wout,
        const float* __restrict__ bout, float* __restrict__ out)
{
  __shared__ float row[SEGF_];
  const int tb = blockIdx.x;
  const int j = threadIdx.x;
  for (int i = j; i < SEGF_; i += 128) row[i] = __int_as_float(pool2[tb*SEGF_ + i]);
  __syncthreads();
  float a = bout[j];
#pragma unroll 8
  for (int k = 0; k < SEGF_; k++) a = fmaf(row[k], Wout[k*HID_ + j], a);
  out[tb*HID_ + j] = fmaxf(a, 0.0f);
}

extern "C" void kernel_launch(void* const* d_in, const int* in_sizes, int n_in,
                              void* d_out, int out_size, void* d_ws, size_t ws_size,
                              hipStream_t stream) {
  const float* pts  = (const float*)d_in[0];
  const float* W1   = (const float*)d_in[1];  const float* b1 = (const float*)d_in[2];
  const float* W2   = (const float*)d_in[3];  const float* b2 = (const float*)d_in[4];
  const float* W3   = (const float*)d_in[5];  const float* b3 = (const float*)d_in[6];
  const float* W4   = (const float*)d_in[7];  const float* b4 = (const float*)d_in[8];
  const float* W5   = (const float*)d_in[9];  const float* b5 = (const float*)d_in[10];
  const float* W6   = (const float*)d_in[11]; const float* b6 = (const float*)d_in[12];
  const float* Wout = (const float*)d_in[13]; const float* bout = (const float*)d_in[14];
  float* out = (float*)d_out;

  char* ws = (char*)d_ws;
  const size_t poolBytes = (size_t)NSEG_ * H_ * sizeof(int);     // 327680
  int* pool1 = (int*)ws;
  int* pool2 = (int*)(ws + poolBytes);
  const size_t baseBytes = 2 * poolBytes;                        // 16B-aligned
  const size_t hBytes = (size_t)TBN_ * 16;                       // 33.5 MB (bf16x8)
  const size_t tBytes = (size_t)TBN_;                            // 2 MB
  const bool useH = ws_size >= baseBytes + hBytes + tBytes;
  uint4* hbuf = (uint4*)(ws + baseBytes);
  unsigned char* tbuf = (unsigned char*)(ws + baseBytes + hBytes);

  hipMemsetAsync(ws, 0, 2 * poolBytes, stream);                  // 0 bits == 0.0f

  const int nblk = TBN_ / 256;   // 8192
  kA<<<nblk, 256, 0, stream>>>(pts, W1, b1, W2, b2, W3, b3,
                               pool1, hbuf, tbuf, useH ? 1 : 0);
  if (useH) {
    kB<<<nblk, 256, 0, stream>>>(hbuf, tbuf, pool1,
                                 W4, b4, W5, b5, W6, b6, pool2);
  } else {
    kBrec<<<nblk, 256, 0, stream>>>(pts, W1, b1, W2, b2, W3, b3, pool1,
                                    W4, b4, W5, b5, W6, b6, pool2);
  }
  kC<<<T_*B_, HID_, 0, stream>>>(pool2, Wout, bout, out);
}